// Round 1
// baseline (432.216 us; speedup 1.0000x reference)
//
#include <hip/hip_runtime.h>
#include <math.h>

// Problem constants (fixed by reference):
#define N_  2
#define S_  1024       // seq len == L
#define H_  12
#define D_  64         // head dim == M
#define HIDDEN_ 768    // H_*D_
#define EPS_ 1e-6f

#define CHUNK 64          // s-rows per pv block
#define NS    (S_/CHUNK)  // 16 s-chunks

#define LT 16             // l-rows per ppv block
#define NL (S_/LT)        // 64 l-blocks

// elu(x)+1  (alpha=1): x>0 ? x+1 : exp(x)
__device__ __forceinline__ float elup1(float x) {
    return x > 0.0f ? x + 1.0f : __expf(x);
}

// ---------------------------------------------------------------------------
// Kernel 1: per-chunk partials (deterministic, no atomics):
//   pv_part[n,h,sc,m,d] = sum_{s in chunk sc} p[n,s,h,d] * v[n,s,h,m]
//   psum_part[n,h,sc,d] = sum_{s in chunk sc} p[n,s,h,d]
// grid = N_*H_*NS = 384 blocks of 256 threads.  (unchanged — ~4 us)
// ---------------------------------------------------------------------------
__global__ __launch_bounds__(256) void pv_kernel(
        const float* __restrict__ v,      // [N,S,H,D]
        const float* __restrict__ mask,   // [N,S]
        const float* __restrict__ w,      // [S,HIDDEN]
        float* __restrict__ pv_part,      // [N,H,NS,64,64]
        float* __restrict__ psum_part) {  // [N,H,NS,64]
    __shared__ float p_lds[CHUNK * 64];
    __shared__ float v_lds[CHUNK * 64];

    const int b  = blockIdx.x;
    const int sc = b % NS;
    const int h  = (b / NS) % H_;
    const int n  = b / (NS * H_);
    const int s0 = sc * CHUNK;
    const int t  = threadIdx.x;

    // Stage p-chunk (elu+mask applied) and v-chunk into LDS via float4 loads.
    for (int j = t; j < CHUNK * 16; j += 256) {
        const int row = j >> 4;
        const int c4  = (j & 15) * 4;
        const int s   = s0 + row;
        const float m = mask[n * S_ + s];
        const float4 wv = *(const float4*)(w + (size_t)s * HIDDEN_ + h * 64 + c4);
        float4 p;
        p.x = elup1(wv.x) * m;
        p.y = elup1(wv.y) * m;
        p.z = elup1(wv.z) * m;
        p.w = elup1(wv.w) * m;
        *(float4*)(p_lds + row * 64 + c4) = p;
        const float4 vv = *(const float4*)(v + (((size_t)n * S_ + s) * H_ + h) * 64 + c4);
        *(float4*)(v_lds + row * 64 + c4) = vv;
    }
    __syncthreads();

    // Outer-product accumulate: thread (d = t&63, mq = t>>6) owns m = mq*16..+15.
    const int d  = t & 63;
    const int mq = t >> 6;
    float acc[16];
    #pragma unroll
    for (int i = 0; i < 16; ++i) acc[i] = 0.0f;
    float ps = 0.0f;

    for (int s = 0; s < CHUNK; ++s) {
        const float pd = p_lds[s * 64 + d];          // stride-1: conflict-free
        ps += pd;
        const float* vr = v_lds + s * 64 + mq * 16;  // wave-uniform: broadcast
        #pragma unroll
        for (int i = 0; i < 16; ++i)
            acc[i] = fmaf(pd, vr[i], acc[i]);
    }

    float* pvp = pv_part + (((size_t)(n * H_ + h)) * NS + sc) * (64 * 64);
    #pragma unroll
    for (int i = 0; i < 16; ++i)
        pvp[(mq * 16 + i) * 64 + d] = acc[i];        // coalesced stores
    if (mq == 0)
        psum_part[(((size_t)(n * H_ + h)) * NS + sc) * 64 + d] = ps;
}

// ---------------------------------------------------------------------------
// Kernel 2: reduce chunk-partials AND compute z (moved out of the hot kernel).
//   grid = N_*H_*4 = 96 blocks of 256 threads; block (n,h,q):
//     - reduces quarter q of the 64x64 pv tile
//     - computes psum[d] into LDS (redundant per q, 1 KB read)
//     - computes z[n,l,h] for l = q*256 .. q*256+255
// ---------------------------------------------------------------------------
__global__ __launch_bounds__(256) void reduce_z_kernel(
        const float* __restrict__ pv_part,    // [N,H,NS,64,64]
        const float* __restrict__ psum_part,  // [N,H,NS,64]
        const float* __restrict__ w,          // [S,HIDDEN]
        const float* __restrict__ mask,       // [N,S]
        float* __restrict__ pv_ws,            // [N,H,64,64]
        float* __restrict__ z_out) {          // [N,S,H]
    __shared__ float psum_lds[64];

    const int b  = blockIdx.x;
    const int q  = b & 3;
    const int h  = (b >> 2) % H_;
    const int n  = b / (4 * H_);
    const int nh = n * H_ + h;
    const int t  = threadIdx.x;

    // psum[d] = sum_sc psum_part  (threads 0..63)
    if (t < 64) {
        const float* ps = psum_part + (size_t)nh * NS * 64 + t;
        float s = 0.0f;
        #pragma unroll
        for (int sc = 0; sc < NS; ++sc)
            s += ps[sc * 64];
        psum_lds[t] = s;
    }

    // reduce quarter-tile: elements q*1024 + t + k*256
    const float* src = pv_part + (size_t)nh * NS * 4096 + q * 1024;
    float* dst = pv_ws + (size_t)nh * 4096 + q * 1024;
    #pragma unroll
    for (int k = 0; k < 4; ++k) {
        const int e = t + k * 256;
        float s = 0.0f;
        #pragma unroll
        for (int sc = 0; sc < NS; ++sc)
            s += src[(size_t)sc * 4096 + e];
        dst[e] = s;
    }
    __syncthreads();

    // z for one l per thread: z = mask * sum_d elup1(w[l,h,d]) * psum[d] + eps
    const int l = q * 256 + t;
    const float m = mask[n * S_ + l];
    const float4* wr = (const float4*)(w + (size_t)l * HIDDEN_ + h * 64);
    float acc = 0.0f;
    #pragma unroll
    for (int i = 0; i < 16; ++i) {
        const float4 wv = wr[i];
        acc += elup1(wv.x) * psum_lds[i * 4 + 0];   // broadcast LDS reads
        acc += elup1(wv.y) * psum_lds[i * 4 + 1];
        acc += elup1(wv.z) * psum_lds[i * 4 + 2];
        acc += elup1(wv.w) * psum_lds[i * 4 + 3];
    }
    z_out[(n * S_ + l) * H_ + h] = acc * m + EPS_;
}

// ---------------------------------------------------------------------------
// Kernel 3: pure streaming ppv. One block per (n, h, 16 l-rows):
//   - pv tile (x head_mask) hoisted into 4 float4 REGISTERS per thread, once
//   - 16 p-rows staged in LDS, once
//   - then 16 iterations of {1 ds_read_b128 + 16 v_mul + 4 dwordx4 stores}
// grid = N_*H_*NL = 1536 blocks x 256 threads; 256 KB written per block.
// ---------------------------------------------------------------------------
__global__ __launch_bounds__(256) void ppv_kernel(
        const float* __restrict__ w,         // [S,HIDDEN]
        const float* __restrict__ mask,      // [N,S]
        const float* __restrict__ head_mask, // [H]
        const float* __restrict__ pv_ws,     // [N,H,64,64]
        float* __restrict__ ppv_out) {       // [N,L,H,64,64]
    __shared__ float p_lds[LT * 64];

    const int b  = blockIdx.x;
    const int h  = b % H_;
    const int lb = (b / H_) % NL;
    const int n  = b / (H_ * NL);
    const int l0 = lb * LT;
    const int t  = threadIdx.x;

    // pv tile into registers, pre-scaled by head_mask (reused for all 16 l).
    const float hm = head_mask[h];
    const float4* pv4 = (const float4*)(pv_ws + ((size_t)(n * H_ + h)) * 4096);
    float4 pr[4];
    #pragma unroll
    for (int jj = 0; jj < 4; ++jj) {
        float4 vv = pv4[t + jj * 256];
        vv.x *= hm; vv.y *= hm; vv.z *= hm; vv.w *= hm;
        pr[jj] = vv;
    }

    // Stage p rows for the 16 l's of this block (1 value per thread per pass).
    const int d  = t & 63;
    const int lw = t >> 6;
    #pragma unroll
    for (int lq = 0; lq < LT / 4; ++lq) {
        const int l = lq * 4 + lw;
        const float m = mask[n * S_ + l0 + l];
        p_lds[l * 64 + d] =
            elup1(w[(size_t)(l0 + l) * HIDDEN_ + h * 64 + d]) * m;  // coalesced 256B/row
    }
    __syncthreads();

    // Stream: thread's d-range is fixed across l and jj (d0 = (4t)&63).
    const int d0 = (t * 4) & 63;
    float4* outb = (float4*)ppv_out + ((size_t)(n * S_ + l0) * H_ + h) * 1024;
    #pragma unroll 4
    for (int l = 0; l < LT; ++l) {
        const float4 pw = *(const float4*)(p_lds + l * 64 + d0);  // broadcast-friendly
        float4* o = outb + (size_t)l * (H_ * 1024);
        #pragma unroll
        for (int jj = 0; jj < 4; ++jj) {
            float4 r;
            r.x = pw.x * pr[jj].x;
            r.y = pw.y * pr[jj].y;
            r.z = pw.z * pr[jj].z;
            r.w = pw.w * pr[jj].w;
            o[t + jj * 256] = r;                     // coalesced 16B/lane stores
        }
    }
}

extern "C" void kernel_launch(void* const* d_in, const int* in_sizes, int n_in,
                              void* d_out, int out_size, void* d_ws, size_t ws_size,
                              hipStream_t stream) {
    // setup_inputs order: q, v, attention_mask, head_mask, pos_weight
    const float* v     = (const float*)d_in[1];
    const float* mask  = (const float*)d_in[2];
    const float* hmask = (const float*)d_in[3];
    const float* w     = (const float*)d_in[4];
    float* out = (float*)d_out;

    // ws layout (floats):
    //   pv_part   : N*H*NS*64*64   = 1,572,864
    //   psum_part : N*H*NS*64      = 24,576
    //   pv_ws     : N*H*64*64      = 98,304
    float* pv_part   = (float*)d_ws;
    float* psum_part = pv_part + (size_t)N_ * H_ * NS * 64 * 64;
    float* pv_ws     = psum_part + (size_t)N_ * H_ * NS * 64;

    float* z_out = out + (size_t)N_ * S_ * H_ * 64 * 64;

    pv_kernel<<<dim3(N_ * H_ * NS), dim3(256), 0, stream>>>(
        v, mask, w, pv_part, psum_part);

    reduce_z_kernel<<<dim3(N_ * H_ * 4), dim3(256), 0, stream>>>(
        pv_part, psum_part, w, mask, pv_ws, z_out);

    ppv_kernel<<<dim3(N_ * H_ * NL), dim3(256), 0, stream>>>(
        w, mask, hmask, pv_ws, out);
}